// Round 11
// baseline (934.678 us; speedup 1.0000x reference)
//
#include <hip/hip_runtime.h>
#include <math.h>

#define RED_BLOCKS 256
#define SB 1024            // scatter blocks
#define NT 512             // fused-kernel threads per block
#define NW 8               // waves per block
#define MAXCOL 32          // ctrl words (cursors; spill cursor at [31])
#define ASH 13
#define ACH (1 << ASH)     // 8192 nodes per bin
#define AKS 32             // reduce sub-blocks per column
#define REDT 512           // reduce threads per block
#define BCAP 192           // per-column LDS staging capacity (entries)
#define CAPA ((1u << 18) + (1u << 14))   // per-column capacity (mean 262K + 33sigma)
#define SPILLCAP (1u << 20)
#define ORD_OFF 0x007fffffu  // f2ord_raw(-inf); shifted so 0 == "-inf"

// Monotone order-preserving float->uint mapping, shifted so 0 means -inf.
__device__ __forceinline__ unsigned f2ord(float f) {
    unsigned u = __float_as_uint(f);
    u = (u & 0x80000000u) ? ~u : (u | 0x80000000u);
    return u - ORD_OFF;
}
__device__ __forceinline__ float ord2f(unsigned uo) {
    unsigned u = uo + ORD_OFF;
    unsigned v = (u & 0x80000000u) ? (u & 0x7fffffffu) : ~u;
    return __uint_as_float(v);
}

__device__ __forceinline__ void h_row_body(const float* __restrict__ loss,
                                           const float* __restrict__ Ws,
                                           float* __restrict__ h,
                                           unsigned* __restrict__ ordArr,
                                           int n, int blk) {
    int sub = threadIdx.x & 15, r = threadIdx.x >> 4;   // 32 rows per 512-thread block
    int row = blk * (NT / 16) + r;
    if (row >= n) return;
    const float4* f4 = (const float4*)(loss + (size_t)row * 200);
    const float4* W4 = (const float4*)Ws;
    float4 a, w;
    float acc = 0.0f;
    a = f4[sub];      w = W4[sub];      acc += a.x*w.x + a.y*w.y + a.z*w.z + a.w*w.w;
    a = f4[sub + 16]; w = W4[sub + 16]; acc += a.x*w.x + a.y*w.y + a.z*w.z + a.w*w.w;
    a = f4[sub + 32]; w = W4[sub + 32]; acc += a.x*w.x + a.y*w.y + a.z*w.z + a.w*w.w;
    if (sub < 2) { a = f4[48 + sub]; w = W4[48 + sub]; acc += a.x*w.x + a.y*w.y + a.z*w.z + a.w*w.w; }
    #pragma unroll
    for (int off = 8; off > 0; off >>= 1) acc += __shfl_down(acc, off, 16);
    if (sub == 0) { h[row] = acc; ordArr[row] = f2ord(acc); }
}

// Standalone h (fallback path).
__global__ void __launch_bounds__(NT) k_h(const float* __restrict__ loss,
                                          const float* __restrict__ Ws,
                                          float* __restrict__ h,
                                          unsigned* __restrict__ ordArr, int n) {
    h_row_body(loss, Ws, h, ordArr, n, blockIdx.x);
}

// Fused kernel. Blocks [0,Gh): h + ordArr. Blocks [Gh,Gh+SB): single-pass
// index-only scatter with LDS-staged coalesced flushes.
//   push: LDS atomicAdd on per-col count -> slot in per-col LDS buffer.
//   flush (per iter, per wave-owned col): one global atomicAdd reserves a
//   dense range; 64-entry multiples written COALESCED. Remainder carried.
// Entry = (other_node << 13) | (node & 8191) -- 4B, no h access here.
// Bucket fill order nondeterministic; per-column content is a fixed set ->
// max is exact & deterministic.
__global__ void __launch_bounds__(NT) k_h_scatter(
        const float* __restrict__ loss, const float* __restrict__ Ws,
        float* __restrict__ h, unsigned* __restrict__ ordArr,
        const int* __restrict__ src, const int* __restrict__ dst,
        unsigned* __restrict__ ctrl, unsigned* __restrict__ buckets,
        uint2* __restrict__ spill, int n, int ne, int nbin, int Gh, int epb) {
    __shared__ unsigned cnt[MAXCOL];
    __shared__ unsigned buf[MAXCOL * BCAP];   // 24 KB
    if ((int)blockIdx.x < Gh) {
        h_row_body(loss, Ws, h, ordArr, n, blockIdx.x);
        return;
    }
    int ncol = 2 * nbin;
    for (int t = threadIdx.x; t < ncol; t += NT) cnt[t] = 0u;
    __syncthreads();
    int cb = blockIdx.x - Gh;
    int s0 = cb * epb, s1 = min(s0 + epb, ne);
    int iters = (epb + NT - 1) / NT;
    int lane = threadIdx.x & 63, wv = threadIdx.x >> 6;

    for (int it = 0; it < iters; ++it) {
        int i = s0 + it * NT + (int)threadIdx.x;
        if (i < s1) {
            int s = src[i], d = dst[i];
            if (s != d) {
                int c0 = d >> ASH;
                unsigned e0 = ((unsigned)s << ASH) | ((unsigned)d & (ACH - 1));
                unsigned p0 = atomicAdd(&cnt[c0], 1u);
                if (p0 < BCAP) buf[c0 * BCAP + p0] = e0;
                else { unsigned g = atomicAdd(&ctrl[c0], 1u);
                       if (g < CAPA) buckets[(size_t)c0 * CAPA + g] = e0;
                       else { unsigned sp = atomicAdd(&ctrl[MAXCOL - 1], 1u);
                              if (sp < SPILLCAP) spill[sp] = make_uint2((unsigned)c0, e0); } }
                int c1 = nbin + (s >> ASH);
                unsigned e1 = ((unsigned)d << ASH) | ((unsigned)s & (ACH - 1));
                unsigned p1 = atomicAdd(&cnt[c1], 1u);
                if (p1 < BCAP) buf[c1 * BCAP + p1] = e1;
                else { unsigned g = atomicAdd(&ctrl[c1], 1u);
                       if (g < CAPA) buckets[(size_t)c1 * CAPA + g] = e1;
                       else { unsigned sp = atomicAdd(&ctrl[MAXCOL - 1], 1u);
                              if (sp < SPILLCAP) spill[sp] = make_uint2((unsigned)c1, e1); } }
            }
        }
        __syncthreads();
        // partial flush: 64-entry multiples, coalesced
        for (int c = wv; c < ncol; c += NW) {
            unsigned n_c = min(cnt[c], (unsigned)BCAP);
            unsigned f = n_c & ~63u;
            if (f) {
                unsigned base = 0;
                if (lane == 0) base = atomicAdd(&ctrl[c], f);
                base = (unsigned)__shfl((int)base, 0);
                for (unsigned k = lane; k < f; k += 64) {
                    unsigned e = buf[c * BCAP + k];
                    unsigned p = base + k;
                    if (p < CAPA) buckets[(size_t)c * CAPA + p] = e;
                    else { unsigned sp = atomicAdd(&ctrl[MAXCOL - 1], 1u);
                           if (sp < SPILLCAP) spill[sp] = make_uint2((unsigned)c, e); }
                }
                unsigned rem = n_c - f;   // < 64
                for (unsigned k = lane; k < rem; k += 64) buf[c * BCAP + k] = buf[c * BCAP + f + k];
                if (lane == 0) cnt[c] = rem;
            }
        }
        __syncthreads();
    }
    // final flush: everything left (< 64 per column)
    for (int c = wv; c < ncol; c += NW) {
        unsigned f = min(cnt[c], (unsigned)BCAP);
        if (f) {
            unsigned base = 0;
            if (lane == 0) base = atomicAdd(&ctrl[c], f);
            base = (unsigned)__shfl((int)base, 0);
            for (unsigned k = lane; k < f; k += 64) {
                unsigned e = buf[c * BCAP + k];
                unsigned p = base + k;
                if (p < CAPA) buckets[(size_t)c * CAPA + p] = e;
                else { unsigned sp = atomicAdd(&ctrl[MAXCOL - 1], 1u);
                       if (sp < SPILLCAP) spill[sp] = make_uint2((unsigned)c, e); }
            }
        }
    }
}

// One WG per (col, ks): stream a 1/AKS slice (coalesced), gather ordArr[other]
// (the only scattered access, now confined here), LDS max, write partial.
__global__ void __launch_bounds__(REDT) k_reduce(
        const unsigned* __restrict__ buckets, const unsigned* __restrict__ ctrl,
        const uint2* __restrict__ spill, const unsigned* __restrict__ ordArr,
        unsigned* __restrict__ partials, int nbin) {
    __shared__ unsigned lds[ACH];
    int col = blockIdx.x / AKS, ks = blockIdx.x - col * AKS;
    for (int t = threadIdx.x; t < ACH; t += REDT) lds[t] = 0u;
    __syncthreads();
    unsigned len = min(ctrl[col], CAPA);
    unsigned a = (unsigned)(((unsigned long long)len * ks) / AKS);
    unsigned b = (unsigned)(((unsigned long long)len * (ks + 1)) / AKS);
    const unsigned* cbp = buckets + (size_t)col * CAPA;
    unsigned i = a + threadIdx.x;
    for (; i + 3u * REDT < b; i += 4u * REDT) {   // 4 chains in flight
        unsigned e0 = cbp[i], e1 = cbp[i + REDT], e2 = cbp[i + 2u * REDT], e3 = cbp[i + 3u * REDT];
        unsigned v0 = ordArr[e0 >> ASH], v1 = ordArr[e1 >> ASH];
        unsigned v2 = ordArr[e2 >> ASH], v3 = ordArr[e3 >> ASH];
        atomicMax(&lds[e0 & (ACH - 1)], v0);
        atomicMax(&lds[e1 & (ACH - 1)], v1);
        atomicMax(&lds[e2 & (ACH - 1)], v2);
        atomicMax(&lds[e3 & (ACH - 1)], v3);
    }
    for (; i < b; i += REDT) {
        unsigned e = cbp[i];
        atomicMax(&lds[e & (ACH - 1)], ordArr[e >> ASH]);
    }
    if (ks == 0) {  // spill entries (normally zero)
        unsigned sc = min(ctrl[MAXCOL - 1], (unsigned)SPILLCAP);
        for (unsigned j = threadIdx.x; j < sc; j += REDT) {
            uint2 e = spill[j];
            if ((int)e.x == col) atomicMax(&lds[e.y & (ACH - 1)], ordArr[e.y >> ASH]);
        }
    }
    __syncthreads();
    unsigned* outp = partials + (size_t)blockIdx.x * ACH;
    for (int t = threadIdx.x; t < ACH; t += REDT) outp[t] = lds[t];
}

// ---- Fallback: device-scope filtered atomics ----
__global__ void k_edges_dev(const int* __restrict__ src, const int* __restrict__ dst,
                            const float* __restrict__ h, unsigned* __restrict__ partials, int ne) {
    int e = blockIdx.x * blockDim.x + threadIdx.x;
    if (e >= ne) return;
    int s = src[e], d = dst[e];
    if (s == d) return;
    unsigned hs = f2ord(h[s]);
    unsigned hd = f2ord(h[d]);
    unsigned* slot0 = &partials[d];
    unsigned* slot1 = &partials[(1 << 17) + s];
    if (*slot0 < hs) atomicMax(slot0, hs);
    if (*slot1 < hd) atomicMax(slot1, hd);
}

// Fold ks x 2 partials, logit = h + w0*pre + w1*suc (0 == empty -> 0.0 fill),
// block-partial max (fixed RED_BLOCKS grid).
__global__ void k_logit_max(const float* __restrict__ h, const unsigned* __restrict__ partials,
                            const float* __restrict__ Wg, float* __restrict__ logit,
                            float* __restrict__ maxPart, int n, int nbin, int ks, int shift) {
    __shared__ float sm[256];
    float w0 = Wg[0], w1 = Wg[1];
    unsigned mask = (1u << shift) - 1;
    size_t CH = (size_t)1 << shift;
    float m = -INFINITY;
    for (int i = blockIdx.x * 256 + threadIdx.x; i < n; i += 256 * RED_BLOCKS) {
        int chunk = i >> shift, off = i & mask;
        size_t b0 = ((size_t)chunk * ks) * CH + off;
        size_t b1 = ((size_t)(nbin + chunk) * ks) * CH + off;
        unsigned p = 0, s = 0;
        #pragma unroll 4
        for (int k = 0; k < ks; ++k) {
            p = max(p, partials[b0 + (size_t)k * CH]);
            s = max(s, partials[b1 + (size_t)k * CH]);
        }
        float pf = p ? ord2f(p) : 0.0f;
        float sf = s ? ord2f(s) : 0.0f;
        float l = h[i] + w0 * pf + w1 * sf;
        logit[i] = l;
        m = fmaxf(m, l);
    }
    sm[threadIdx.x] = m;
    __syncthreads();
    for (int off = 128; off > 0; off >>= 1) {
        if (threadIdx.x < off) sm[threadIdx.x] = fmaxf(sm[threadIdx.x], sm[threadIdx.x + off]);
        __syncthreads();
    }
    if (threadIdx.x == 0) maxPart[blockIdx.x] = sm[0];
}

__global__ void k_exp_sum(const float* __restrict__ logit, const float* __restrict__ maxPart,
                          float* __restrict__ out, float* __restrict__ sumPart, int n) {
    __shared__ float sm[256];
    sm[threadIdx.x] = maxPart[threadIdx.x];
    __syncthreads();
    for (int off = 128; off > 0; off >>= 1) {
        if (threadIdx.x < off) sm[threadIdx.x] = fmaxf(sm[threadIdx.x], sm[threadIdx.x + off]);
        __syncthreads();
    }
    float gmax = sm[0];
    __syncthreads();
    float acc = 0.0f;
    for (int i = blockIdx.x * 256 + threadIdx.x; i < n; i += 256 * RED_BLOCKS) {
        float e = expf(logit[i] - gmax);
        out[i] = e;
        acc += e;
    }
    sm[threadIdx.x] = acc;
    __syncthreads();
    for (int off = 128; off > 0; off >>= 1) {
        if (threadIdx.x < off) sm[threadIdx.x] += sm[threadIdx.x + off];
        __syncthreads();
    }
    if (threadIdx.x == 0) sumPart[blockIdx.x] = sm[0];
}

__global__ void k_norm(const float* __restrict__ sumPart, float* __restrict__ out, int n) {
    __shared__ float sm[256];
    sm[threadIdx.x] = sumPart[threadIdx.x];
    __syncthreads();
    for (int off = 128; off > 0; off >>= 1) {
        if (threadIdx.x < off) sm[threadIdx.x] += sm[threadIdx.x + off];
        __syncthreads();
    }
    float inv = 1.0f / sm[0];
    for (int i = blockIdx.x * 256 + threadIdx.x; i < n; i += 256 * RED_BLOCKS) out[i] *= inv;
}

extern "C" void kernel_launch(void* const* d_in, const int* in_sizes, int n_in,
                              void* d_out, int out_size, void* d_ws, size_t ws_size,
                              hipStream_t stream) {
    const float* loss = (const float*)d_in[0];   // [N, 200]
    const float* Ws   = (const float*)d_in[1];   // [1, 200]
    const float* Wg   = (const float*)d_in[2];   // [1, 2]
    const int* esrc   = (const int*)d_in[3];     // [E]
    const int* edst   = (const int*)d_in[4];     // [E]
    float* out = (float*)d_out;                  // [N]

    const int n  = in_sizes[0] / 200;
    const int ne = in_sizes[3];
    const int epb = (ne + SB - 1) / SB;          // edges per scatter block
    const int Gh  = (n + (NT / 16) - 1) / (NT / 16);

    const int nbin = (n + ACH - 1) >> ASH, ncol = 2 * nbin;

    // ws layout (32-bit words):
    // h[n] | logit[n] | ordArr[n] | maxPart | sumPart | ctrl[32] |
    // partials[ncol*AKS*ACH] | buckets[ncol*CAPA] (u32) | spill[SPILLCAP] (uint2)
    float*    h        = (float*)d_ws;
    float*    logit    = h + n;
    unsigned* ordArr   = (unsigned*)(logit + n);
    float*    maxPart  = (float*)(ordArr + n);
    float*    sumPart  = maxPart + RED_BLOCKS;
    unsigned* ctrl     = (unsigned*)(sumPart + RED_BLOCKS);
    unsigned* partials = ctrl + MAXCOL;
    size_t part_w = (size_t)ncol * AKS * ACH;
    unsigned* buckets  = partials + part_w;
    uint2*    spill    = (uint2*)(buckets + (size_t)ncol * CAPA);
    size_t need = ((size_t)3 * n + 2 * RED_BLOCKS + MAXCOL + part_w + (size_t)ncol * CAPA) * 4
                + (size_t)SPILLCAP * 8;

    if (need <= ws_size && ncol < MAXCOL - 1 && n <= (1 << 17)) {
        hipMemsetAsync(ctrl, 0, MAXCOL * sizeof(unsigned), stream);
        k_h_scatter<<<Gh + SB, NT, 0, stream>>>(loss, Ws, h, ordArr, esrc, edst,
                                                ctrl, buckets, spill, n, ne, nbin, Gh, epb);
        k_reduce<<<ncol * AKS, REDT, 0, stream>>>(buckets, ctrl, spill, ordArr, partials, nbin);
        k_logit_max<<<RED_BLOCKS, 256, 0, stream>>>(h, partials, Wg, logit, maxPart, n, nbin, AKS, ASH);
    } else {
        k_h<<<Gh, NT, 0, stream>>>(loss, Ws, h, ordArr, n);
        hipMemsetAsync(partials, 0, (size_t)2 * (1 << 17) * 4, stream);
        k_edges_dev<<<(ne + 255) / 256, 256, 0, stream>>>(esrc, edst, h, partials, ne);
        k_logit_max<<<RED_BLOCKS, 256, 0, stream>>>(h, partials, Wg, logit, maxPart, n, 1, 1, 17);
    }

    k_exp_sum<<<RED_BLOCKS, 256, 0, stream>>>(logit, maxPart, out, sumPart, n);
    k_norm<<<RED_BLOCKS, 256, 0, stream>>>(sumPart, out, n);
}

// Round 12
// 157.574 us; speedup vs baseline: 5.9317x; 5.9317x over previous
//
#include <hip/hip_runtime.h>
#include <math.h>

#define RED_BLOCKS 256
#define SB 1024            // scatter blocks
#define NT 512             // fused-kernel threads per block
#define NW 8               // waves per block
#define ASH 13
#define ACH (1 << ASH)     // 8192 nodes per bin
#define NBINMAX 13         // fast path requires n <= 13*8192 = 106496
#define NCOLMAX (NBINMAX * NBINMAX)
#define BCAP 76            // per-col LDS staging (mean 18.5/col/block; P(>76)~0)
#define NSUBC 8            // sub-cursors per column (kills reservation contention)
#define SCAP 16384         // per-(col,sub) bucket capacity (mean 2368, 7x slack)
#define SPILLCAP (1u << 20)
#define REDT 512
#define ORD_OFF 0x007fffffu  // f2ord(-inf); shifted so 0 == "-inf"/empty

// Monotone order-preserving float->uint mapping, shifted so 0 means -inf.
__device__ __forceinline__ unsigned f2ord(float f) {
    unsigned u = __float_as_uint(f);
    u = (u & 0x80000000u) ? ~u : (u | 0x80000000u);
    return u - ORD_OFF;
}
__device__ __forceinline__ float ord2f(unsigned uo) {
    unsigned u = uo + ORD_OFF;
    unsigned v = (u & 0x80000000u) ? (u & 0x7fffffffu) : ~u;
    return __uint_as_float(v);
}

template <class F>
__device__ __forceinline__ void for_each_edge(const int* __restrict__ src,
                                              const int* __restrict__ dst,
                                              int s0, int s1, F f) {
    for (int i = s0 + threadIdx.x * 4; i < s1; i += blockDim.x * 4) {
        if (i + 3 < s1) {
            int4 a = *(const int4*)(src + i);
            int4 b = *(const int4*)(dst + i);
            f(a.x, b.x); f(a.y, b.y); f(a.z, b.z); f(a.w, b.w);
        } else {
            for (int j = i; j < s1 && j < i + 4; ++j) f(src[j], dst[j]);
        }
    }
}

__device__ __forceinline__ void h_row_body(const float* __restrict__ loss,
                                           const float* __restrict__ Ws,
                                           float* __restrict__ h,
                                           unsigned* __restrict__ ordArr,
                                           int n, int blk) {
    int sub = threadIdx.x & 15, r = threadIdx.x >> 4;   // 32 rows per 512-thread block
    int row = blk * (NT / 16) + r;
    if (row >= n) return;
    const float4* f4 = (const float4*)(loss + (size_t)row * 200);
    const float4* W4 = (const float4*)Ws;
    float4 a, w;
    float acc = 0.0f;
    a = f4[sub];      w = W4[sub];      acc += a.x*w.x + a.y*w.y + a.z*w.z + a.w*w.w;
    a = f4[sub + 16]; w = W4[sub + 16]; acc += a.x*w.x + a.y*w.y + a.z*w.z + a.w*w.w;
    a = f4[sub + 32]; w = W4[sub + 32]; acc += a.x*w.x + a.y*w.y + a.z*w.z + a.w*w.w;
    if (sub < 2) { a = f4[48 + sub]; w = W4[48 + sub]; acc += a.x*w.x + a.y*w.y + a.z*w.z + a.w*w.w; }
    #pragma unroll
    for (int off = 8; off > 0; off >>= 1) acc += __shfl_down(acc, off, 16);
    if (sub == 0) { h[row] = acc; ordArr[row] = f2ord(acc); }
}

__global__ void __launch_bounds__(NT) k_h(const float* __restrict__ loss,
                                          const float* __restrict__ Ws,
                                          float* __restrict__ h,
                                          unsigned* __restrict__ ordArr, int n) {
    h_row_body(loss, Ws, h, ordArr, n, blockIdx.x);
}

// Fused. Blocks [0,Gh): h + ordArr. Blocks [Gh,Gh+SB): single-pass 2-D binning.
// One 4B entry per edge into bucket (sb,db): (srcLocal<<13)|dstLocal.
// LDS-staged (mean 18.5/col/block), ONE coalesced flush at block end.
// Reservation: 1 atomicAdd per (block,col) on NSUBC sub-cursors -> <=128
// atomics per word (round-11 lesson). Bucket CONTENT per (col,sub) is a fixed
// set regardless of atomic order -> max-reduce exact & deterministic.
__global__ void __launch_bounds__(NT) k_h_scatter(
        const float* __restrict__ loss, const float* __restrict__ Ws,
        float* __restrict__ h, unsigned* __restrict__ ordArr,
        const int* __restrict__ src, const int* __restrict__ dst,
        unsigned* __restrict__ ctrl, unsigned* __restrict__ buckets,
        uint2* __restrict__ spill, int n, int ne, int nbin, int ncol,
        int Gh, int epb) {
    __shared__ unsigned cnt[NCOLMAX];
    __shared__ unsigned buf[NCOLMAX * BCAP];   // ~51 KB
    if ((int)blockIdx.x < Gh) {
        h_row_body(loss, Ws, h, ordArr, n, blockIdx.x);
        return;
    }
    int cb = blockIdx.x - Gh;
    for (int t = threadIdx.x; t < ncol; t += NT) cnt[t] = 0u;
    __syncthreads();
    int s0 = cb * epb, s1 = min(s0 + epb, ne);
    for_each_edge(src, dst, s0, s1, [&](int s, int d) {
        if (s != d) {
            int col = (s >> ASH) * nbin + (d >> ASH);
            unsigned e = ((unsigned)(s & (ACH - 1)) << ASH) | (unsigned)(d & (ACH - 1));
            unsigned p = atomicAdd(&cnt[col], 1u);
            if (p < BCAP) buf[col * BCAP + p] = e;
            else { unsigned sp = atomicAdd(&ctrl[ncol * NSUBC], 1u);
                   if (sp < SPILLCAP) spill[sp] = make_uint2((unsigned)col, e); }
        }
    });
    __syncthreads();
    int lane = threadIdx.x & 63, wv = threadIdx.x >> 6;
    int j = cb & (NSUBC - 1);
    for (int c = wv; c < ncol; c += NW) {
        unsigned tot = min(cnt[c], (unsigned)BCAP);
        if (!tot) continue;
        unsigned base = 0;
        if (lane == 0) base = atomicAdd(&ctrl[c * NSUBC + j], tot);
        base = (unsigned)__shfl((int)base, 0);
        unsigned* bp = buckets + ((size_t)c * NSUBC + j) * SCAP;
        for (unsigned k = lane; k < tot; k += 64) {
            unsigned pos = base + k;
            unsigned e = buf[c * BCAP + k];
            if (pos < SCAP) bp[pos] = e;
            else { unsigned sp = atomicAdd(&ctrl[ncol * NSUBC], 1u);
                   if (sp < SPILLCAP) spill[sp] = make_uint2((unsigned)c, e); }
        }
    }
}

// One WG per (dir, col=(sb,db)). Preload ord[value-slice] into LDS (32KB),
// stream the bucket's 8 sub-regions coalesced, LDS-max into acc, write an
// 8192-word partial. dir0 (pre): val=sb-slice, acc[dstLocal], partial (db,sb).
// dir1 (suc): val=db-slice, acc[srcLocal], partial (sb,db). No global gathers.
__global__ void __launch_bounds__(REDT) k_reduce(
        const unsigned* __restrict__ buckets, const unsigned* __restrict__ ctrl,
        const uint2* __restrict__ spill, const unsigned* __restrict__ ordArr,
        unsigned* __restrict__ partials, int n, int nbin, int ncol) {
    __shared__ unsigned vals[ACH];
    __shared__ unsigned acc[ACH];
    int dir = blockIdx.x / ncol;
    int col = blockIdx.x - dir * ncol;
    int sb = col / nbin, db = col - sb * nbin;
    int vbin = dir ? db : sb;
    for (int t = threadIdx.x; t < ACH; t += REDT) {
        int g = (vbin << ASH) + t;
        vals[t] = (g < n) ? ordArr[g] : 0u;
        acc[t] = 0u;
    }
    __syncthreads();
    for (int j = 0; j < NSUBC; ++j) {
        unsigned len = min(ctrl[col * NSUBC + j], (unsigned)SCAP);
        const unsigned* bp = buckets + ((size_t)col * NSUBC + j) * SCAP;
        unsigned i = threadIdx.x;
        for (; i + 3u * REDT < len; i += 4u * REDT) {
            unsigned e0 = bp[i], e1 = bp[i + REDT], e2 = bp[i + 2u * REDT], e3 = bp[i + 3u * REDT];
            if (dir == 0) {
                atomicMax(&acc[e0 & (ACH - 1)], vals[e0 >> ASH]);
                atomicMax(&acc[e1 & (ACH - 1)], vals[e1 >> ASH]);
                atomicMax(&acc[e2 & (ACH - 1)], vals[e2 >> ASH]);
                atomicMax(&acc[e3 & (ACH - 1)], vals[e3 >> ASH]);
            } else {
                atomicMax(&acc[e0 >> ASH], vals[e0 & (ACH - 1)]);
                atomicMax(&acc[e1 >> ASH], vals[e1 & (ACH - 1)]);
                atomicMax(&acc[e2 >> ASH], vals[e2 & (ACH - 1)]);
                atomicMax(&acc[e3 >> ASH], vals[e3 & (ACH - 1)]);
            }
        }
        for (; i < len; i += REDT) {
            unsigned e = bp[i];
            if (dir == 0) atomicMax(&acc[e & (ACH - 1)], vals[e >> ASH]);
            else          atomicMax(&acc[e >> ASH], vals[e & (ACH - 1)]);
        }
    }
    unsigned sc = min(ctrl[ncol * NSUBC], (unsigned)SPILLCAP);  // normally 0
    for (unsigned t = threadIdx.x; t < sc; t += REDT) {
        uint2 e = spill[t];
        if ((int)e.x == col) {
            unsigned ee = e.y;
            if (dir == 0) atomicMax(&acc[ee & (ACH - 1)], vals[ee >> ASH]);
            else          atomicMax(&acc[ee >> ASH], vals[ee & (ACH - 1)]);
        }
    }
    __syncthreads();
    size_t pbase = ((size_t)(dir ? ncol : 0) + (dir ? (sb * nbin + db) : (db * nbin + sb))) * ACH;
    for (int t = threadIdx.x; t < ACH; t += REDT) partials[pbase + t] = acc[t];
}

// ---- Fallback: device-scope filtered atomics (pre at [0], suc at [1<<17]) ----
__global__ void k_edges_dev(const int* __restrict__ src, const int* __restrict__ dst,
                            const float* __restrict__ h, unsigned* __restrict__ partials, int ne) {
    int e = blockIdx.x * blockDim.x + threadIdx.x;
    if (e >= ne) return;
    int s = src[e], d = dst[e];
    if (s == d) return;
    unsigned hs = f2ord(h[s]);
    unsigned hd = f2ord(h[d]);
    unsigned* slot0 = &partials[d];
    unsigned* slot1 = &partials[(1 << 17) + s];
    if (*slot0 < hs) atomicMax(slot0, hs);
    if (*slot1 < hd) atomicMax(slot1, hd);
}

// Fast-path fold: pre over sb-partials, suc over db-partials; 0==empty->0.0.
__global__ void k_logit_max(const float* __restrict__ h, const unsigned* __restrict__ partials,
                            const float* __restrict__ Wg, float* __restrict__ logit,
                            float* __restrict__ maxPart, int n, int nbin, int ncol) {
    __shared__ float sm[256];
    float w0 = Wg[0], w1 = Wg[1];
    float m = -INFINITY;
    for (int i = blockIdx.x * 256 + threadIdx.x; i < n; i += 256 * RED_BLOCKS) {
        int bin = i >> ASH, off = i & (ACH - 1);
        const unsigned* pp = partials + (size_t)(bin * nbin) * ACH + off;
        const unsigned* sp = partials + ((size_t)ncol + bin * nbin) * ACH + off;
        unsigned p = 0, s = 0;
        for (int k = 0; k < nbin; ++k) {
            p = max(p, pp[(size_t)k * ACH]);
            s = max(s, sp[(size_t)k * ACH]);
        }
        float pf = p ? ord2f(p) : 0.0f;
        float sf = s ? ord2f(s) : 0.0f;
        float l = h[i] + w0 * pf + w1 * sf;
        logit[i] = l;
        m = fmaxf(m, l);
    }
    sm[threadIdx.x] = m;
    __syncthreads();
    for (int off = 128; off > 0; off >>= 1) {
        if (threadIdx.x < off) sm[threadIdx.x] = fmaxf(sm[threadIdx.x], sm[threadIdx.x + off]);
        __syncthreads();
    }
    if (threadIdx.x == 0) maxPart[blockIdx.x] = sm[0];
}

// Fallback fold (flat pre/suc arrays).
__global__ void k_logit_max_dev(const float* __restrict__ h, const unsigned* __restrict__ partials,
                                const float* __restrict__ Wg, float* __restrict__ logit,
                                float* __restrict__ maxPart, int n) {
    __shared__ float sm[256];
    float w0 = Wg[0], w1 = Wg[1];
    float m = -INFINITY;
    for (int i = blockIdx.x * 256 + threadIdx.x; i < n; i += 256 * RED_BLOCKS) {
        unsigned p = partials[i], s = partials[(1 << 17) + i];
        float pf = p ? ord2f(p) : 0.0f;
        float sf = s ? ord2f(s) : 0.0f;
        float l = h[i] + w0 * pf + w1 * sf;
        logit[i] = l;
        m = fmaxf(m, l);
    }
    sm[threadIdx.x] = m;
    __syncthreads();
    for (int off = 128; off > 0; off >>= 1) {
        if (threadIdx.x < off) sm[threadIdx.x] = fmaxf(sm[threadIdx.x], sm[threadIdx.x + off]);
        __syncthreads();
    }
    if (threadIdx.x == 0) maxPart[blockIdx.x] = sm[0];
}

__global__ void k_exp_sum(const float* __restrict__ logit, const float* __restrict__ maxPart,
                          float* __restrict__ out, float* __restrict__ sumPart, int n) {
    __shared__ float sm[256];
    sm[threadIdx.x] = maxPart[threadIdx.x];
    __syncthreads();
    for (int off = 128; off > 0; off >>= 1) {
        if (threadIdx.x < off) sm[threadIdx.x] = fmaxf(sm[threadIdx.x], sm[threadIdx.x + off]);
        __syncthreads();
    }
    float gmax = sm[0];
    __syncthreads();
    float acc = 0.0f;
    for (int i = blockIdx.x * 256 + threadIdx.x; i < n; i += 256 * RED_BLOCKS) {
        float e = expf(logit[i] - gmax);
        out[i] = e;
        acc += e;
    }
    sm[threadIdx.x] = acc;
    __syncthreads();
    for (int off = 128; off > 0; off >>= 1) {
        if (threadIdx.x < off) sm[threadIdx.x] += sm[threadIdx.x + off];
        __syncthreads();
    }
    if (threadIdx.x == 0) sumPart[blockIdx.x] = sm[0];
}

__global__ void k_norm(const float* __restrict__ sumPart, float* __restrict__ out, int n) {
    __shared__ float sm[256];
    sm[threadIdx.x] = sumPart[threadIdx.x];
    __syncthreads();
    for (int off = 128; off > 0; off >>= 1) {
        if (threadIdx.x < off) sm[threadIdx.x] += sm[threadIdx.x + off];
        __syncthreads();
    }
    float inv = 1.0f / sm[0];
    for (int i = blockIdx.x * 256 + threadIdx.x; i < n; i += 256 * RED_BLOCKS) out[i] *= inv;
}

extern "C" void kernel_launch(void* const* d_in, const int* in_sizes, int n_in,
                              void* d_out, int out_size, void* d_ws, size_t ws_size,
                              hipStream_t stream) {
    const float* loss = (const float*)d_in[0];   // [N, 200]
    const float* Ws   = (const float*)d_in[1];   // [1, 200]
    const float* Wg   = (const float*)d_in[2];   // [1, 2]
    const int* esrc   = (const int*)d_in[3];     // [E]
    const int* edst   = (const int*)d_in[4];     // [E]
    float* out = (float*)d_out;                  // [N]

    const int n  = in_sizes[0] / 200;
    const int ne = in_sizes[3];
    const int epb = (((ne + SB - 1) / SB) + 3) & ~3;
    const int Gh  = (n + (NT / 16) - 1) / (NT / 16);

    const int nbin = (n + ACH - 1) >> ASH;
    const int ncol = nbin * nbin;
    const int nctrl = ncol * NSUBC + 8;

    // ws layout (32-bit words):
    // h[n] | logit[n] | ordArr[n] | maxPart | sumPart | ctrl[nctrl] |
    // partials[2*ncol*ACH] | buckets[ncol*NSUBC*SCAP] | spill[SPILLCAP] (uint2)
    float*    h        = (float*)d_ws;
    float*    logit    = h + n;
    unsigned* ordArr   = (unsigned*)(logit + n);
    float*    maxPart  = (float*)(ordArr + n);
    float*    sumPart  = maxPart + RED_BLOCKS;
    unsigned* ctrl     = (unsigned*)(sumPart + RED_BLOCKS);
    unsigned* partials = ctrl + nctrl;
    size_t part_w = (size_t)2 * ncol * ACH;
    unsigned* buckets  = partials + part_w;
    size_t buck_w = (size_t)ncol * NSUBC * SCAP;
    uint2*    spill    = (uint2*)(buckets + buck_w);
    size_t need = ((size_t)3 * n + 2 * RED_BLOCKS + nctrl + part_w + buck_w) * 4
                + (size_t)SPILLCAP * 8;

    if (need <= ws_size && nbin <= NBINMAX) {
        hipMemsetAsync(ctrl, 0, (size_t)nctrl * 4, stream);
        k_h_scatter<<<Gh + SB, NT, 0, stream>>>(loss, Ws, h, ordArr, esrc, edst,
                                                ctrl, buckets, spill, n, ne, nbin, ncol, Gh, epb);
        k_reduce<<<2 * ncol, REDT, 0, stream>>>(buckets, ctrl, spill, ordArr, partials, n, nbin, ncol);
        k_logit_max<<<RED_BLOCKS, 256, 0, stream>>>(h, partials, Wg, logit, maxPart, n, nbin, ncol);
    } else {
        k_h<<<Gh, NT, 0, stream>>>(loss, Ws, h, ordArr, n);
        hipMemsetAsync(partials, 0, (size_t)2 * (1 << 17) * 4, stream);
        k_edges_dev<<<(ne + 255) / 256, 256, 0, stream>>>(esrc, edst, h, partials, ne);
        k_logit_max_dev<<<RED_BLOCKS, 256, 0, stream>>>(h, partials, Wg, logit, maxPart, n);
    }

    k_exp_sum<<<RED_BLOCKS, 256, 0, stream>>>(logit, maxPart, out, sumPart, n);
    k_norm<<<RED_BLOCKS, 256, 0, stream>>>(sumPart, out, n);
}

// Round 13
// 79.926 us; speedup vs baseline: 11.6943x; 1.9715x over previous
//
#include <hip/hip_runtime.h>
#include <math.h>

#define RED_BLOCKS 256
#define NT 512             // k_h threads
#define AT 1024            // k_accum threads
#define CSH2 14
#define CCH (1 << CSH2)    // 16384 nodes per chunk (64 KB LDS per direction)
#define ORD_OFF 0x007fffffu  // f2ord(-inf); shifted so 0 == "-inf"/empty

// Monotone order-preserving float->uint mapping, shifted so 0 means -inf.
__device__ __forceinline__ unsigned f2ord(float f) {
    unsigned u = __float_as_uint(f);
    u = (u & 0x80000000u) ? ~u : (u | 0x80000000u);
    return u - ORD_OFF;
}
__device__ __forceinline__ float ord2f(unsigned uo) {
    unsigned u = uo + ORD_OFF;
    unsigned v = (u & 0x80000000u) ? (u & 0x7fffffffu) : ~u;
    return __uint_as_float(v);
}

__device__ __forceinline__ void h_row_body(const float* __restrict__ loss,
                                           const float* __restrict__ Ws,
                                           float* __restrict__ h,
                                           unsigned* __restrict__ ordArr,
                                           int n, int blk) {
    int sub = threadIdx.x & 15, r = threadIdx.x >> 4;   // 32 rows per 512-thread block
    int row = blk * (NT / 16) + r;
    if (row >= n) return;
    const float4* f4 = (const float4*)(loss + (size_t)row * 200);
    const float4* W4 = (const float4*)Ws;
    float4 a, w;
    float acc = 0.0f;
    a = f4[sub];      w = W4[sub];      acc += a.x*w.x + a.y*w.y + a.z*w.z + a.w*w.w;
    a = f4[sub + 16]; w = W4[sub + 16]; acc += a.x*w.x + a.y*w.y + a.z*w.z + a.w*w.w;
    a = f4[sub + 32]; w = W4[sub + 32]; acc += a.x*w.x + a.y*w.y + a.z*w.z + a.w*w.w;
    if (sub < 2) { a = f4[48 + sub]; w = W4[48 + sub]; acc += a.x*w.x + a.y*w.y + a.z*w.z + a.w*w.w; }
    #pragma unroll
    for (int off = 8; off > 0; off >>= 1) acc += __shfl_down(acc, off, 16);
    if (sub == 0) { h[row] = acc; ordArr[row] = f2ord(acc); }
}

__global__ void __launch_bounds__(NT) k_h(const float* __restrict__ loss,
                                          const float* __restrict__ Ws,
                                          float* __restrict__ h,
                                          unsigned* __restrict__ ordArr, int n) {
    h_row_body(loss, Ws, h, ordArr, n, blockIdx.x);
}

// Scatter-free segment-max. Block (c, sub): owns node chunk c (16384 nodes,
// BOTH directions in 128 KB LDS) and scans edge slice sub. For each edge:
//   d in chunk -> atomicMax(preL[d&16383], ordArr[s])   (pre: max over in-edges)
//   s in chunk -> atomicMax(sucL[s&16383], ordArr[d])   (suc: max over out-edges)
// Non-returning LDS atomics only (the returning-atomic slot machinery of
// rounds 8-12 was the latency bottleneck); no global atomics; no scattered
// global stores. Edge list re-read nch times, but the nch same-slice blocks
// run concurrently -> L2/L3 serve re-reads (HBM fetch ~= one pass).
// ordArr (400 KB) is L2-resident for the gathers. Exact max, order-free ->
// bit-deterministic.
__global__ void __launch_bounds__(AT) k_accum(
        const int* __restrict__ src, const int* __restrict__ dst,
        const unsigned* __restrict__ ordArr, unsigned* __restrict__ partials,
        int ne, int nch, int split, int epb) {
    __shared__ unsigned preL[CCH];
    __shared__ unsigned sucL[CCH];
    int c = blockIdx.x / split, sub = blockIdx.x - c * split;
    for (int t = threadIdx.x; t < CCH; t += AT) { preL[t] = 0u; sucL[t] = 0u; }
    __syncthreads();
    int lo = sub * epb, hi = min(lo + epb, ne);
    for (int i = lo + (int)threadIdx.x * 4; i < hi; i += AT * 4) {
        if (i + 3 < hi) {
            int4 a = *(const int4*)(src + i);
            int4 b = *(const int4*)(dst + i);
            if (a.x != b.x) {
                if ((b.x >> CSH2) == c) atomicMax(&preL[b.x & (CCH - 1)], ordArr[a.x]);
                if ((a.x >> CSH2) == c) atomicMax(&sucL[a.x & (CCH - 1)], ordArr[b.x]);
            }
            if (a.y != b.y) {
                if ((b.y >> CSH2) == c) atomicMax(&preL[b.y & (CCH - 1)], ordArr[a.y]);
                if ((a.y >> CSH2) == c) atomicMax(&sucL[a.y & (CCH - 1)], ordArr[b.y]);
            }
            if (a.z != b.z) {
                if ((b.z >> CSH2) == c) atomicMax(&preL[b.z & (CCH - 1)], ordArr[a.z]);
                if ((a.z >> CSH2) == c) atomicMax(&sucL[a.z & (CCH - 1)], ordArr[b.z]);
            }
            if (a.w != b.w) {
                if ((b.w >> CSH2) == c) atomicMax(&preL[b.w & (CCH - 1)], ordArr[a.w]);
                if ((a.w >> CSH2) == c) atomicMax(&sucL[a.w & (CCH - 1)], ordArr[b.w]);
            }
        } else {
            for (int j = i; j < hi && j < i + 4; ++j) {
                int s = src[j], d = dst[j];
                if (s != d) {
                    if ((d >> CSH2) == c) atomicMax(&preL[d & (CCH - 1)], ordArr[s]);
                    if ((s >> CSH2) == c) atomicMax(&sucL[s & (CCH - 1)], ordArr[d]);
                }
            }
        }
    }
    __syncthreads();
    size_t pb = ((size_t)c * split + sub) * CCH;
    size_t sucOff = (size_t)nch * split * CCH;
    for (int t = threadIdx.x; t < CCH; t += AT) {
        partials[pb + t] = preL[t];
        partials[sucOff + pb + t] = sucL[t];
    }
}

// ---- Fallback: device-scope filtered atomics (pre at [0], suc at [1<<17]) ----
__global__ void k_edges_dev(const int* __restrict__ src, const int* __restrict__ dst,
                            const float* __restrict__ h, unsigned* __restrict__ partials, int ne) {
    int e = blockIdx.x * blockDim.x + threadIdx.x;
    if (e >= ne) return;
    int s = src[e], d = dst[e];
    if (s == d) return;
    unsigned hs = f2ord(h[s]);
    unsigned hd = f2ord(h[d]);
    unsigned* slot0 = &partials[d];
    unsigned* slot1 = &partials[(1 << 17) + s];
    if (*slot0 < hs) atomicMax(slot0, hs);
    if (*slot1 < hd) atomicMax(slot1, hd);
}

// Fold split partials per direction; logit = h + w0*pre + w1*suc (0 -> 0.0);
// block-partial max (fixed RED_BLOCKS grid).
__global__ void k_logit_max(const float* __restrict__ h, const unsigned* __restrict__ partials,
                            const float* __restrict__ Wg, float* __restrict__ logit,
                            float* __restrict__ maxPart, int n, int nch, int split) {
    __shared__ float sm[256];
    float w0 = Wg[0], w1 = Wg[1];
    size_t sucOff = (size_t)nch * split * CCH;
    float m = -INFINITY;
    for (int i = blockIdx.x * 256 + threadIdx.x; i < n; i += 256 * RED_BLOCKS) {
        int c = i >> CSH2, loc = i & (CCH - 1);
        const unsigned* pp = partials + ((size_t)c * split) * CCH + loc;
        const unsigned* sp = pp + sucOff;
        unsigned p = 0, s = 0;
        #pragma unroll 4
        for (int k = 0; k < split; ++k) {
            p = max(p, pp[(size_t)k * CCH]);
            s = max(s, sp[(size_t)k * CCH]);
        }
        float pf = p ? ord2f(p) : 0.0f;
        float sf = s ? ord2f(s) : 0.0f;
        float l = h[i] + w0 * pf + w1 * sf;
        logit[i] = l;
        m = fmaxf(m, l);
    }
    sm[threadIdx.x] = m;
    __syncthreads();
    for (int off = 128; off > 0; off >>= 1) {
        if (threadIdx.x < off) sm[threadIdx.x] = fmaxf(sm[threadIdx.x], sm[threadIdx.x + off]);
        __syncthreads();
    }
    if (threadIdx.x == 0) maxPart[blockIdx.x] = sm[0];
}

// Fallback fold (flat pre/suc arrays).
__global__ void k_logit_max_dev(const float* __restrict__ h, const unsigned* __restrict__ partials,
                                const float* __restrict__ Wg, float* __restrict__ logit,
                                float* __restrict__ maxPart, int n) {
    __shared__ float sm[256];
    float w0 = Wg[0], w1 = Wg[1];
    float m = -INFINITY;
    for (int i = blockIdx.x * 256 + threadIdx.x; i < n; i += 256 * RED_BLOCKS) {
        unsigned p = partials[i], s = partials[(1 << 17) + i];
        float pf = p ? ord2f(p) : 0.0f;
        float sf = s ? ord2f(s) : 0.0f;
        float l = h[i] + w0 * pf + w1 * sf;
        logit[i] = l;
        m = fmaxf(m, l);
    }
    sm[threadIdx.x] = m;
    __syncthreads();
    for (int off = 128; off > 0; off >>= 1) {
        if (threadIdx.x < off) sm[threadIdx.x] = fmaxf(sm[threadIdx.x], sm[threadIdx.x + off]);
        __syncthreads();
    }
    if (threadIdx.x == 0) maxPart[blockIdx.x] = sm[0];
}

__global__ void k_exp_sum(const float* __restrict__ logit, const float* __restrict__ maxPart,
                          float* __restrict__ out, float* __restrict__ sumPart, int n) {
    __shared__ float sm[256];
    sm[threadIdx.x] = maxPart[threadIdx.x];
    __syncthreads();
    for (int off = 128; off > 0; off >>= 1) {
        if (threadIdx.x < off) sm[threadIdx.x] = fmaxf(sm[threadIdx.x], sm[threadIdx.x + off]);
        __syncthreads();
    }
    float gmax = sm[0];
    __syncthreads();
    float acc = 0.0f;
    for (int i = blockIdx.x * 256 + threadIdx.x; i < n; i += 256 * RED_BLOCKS) {
        float e = expf(logit[i] - gmax);
        out[i] = e;
        acc += e;
    }
    sm[threadIdx.x] = acc;
    __syncthreads();
    for (int off = 128; off > 0; off >>= 1) {
        if (threadIdx.x < off) sm[threadIdx.x] += sm[threadIdx.x + off];
        __syncthreads();
    }
    if (threadIdx.x == 0) sumPart[blockIdx.x] = sm[0];
}

__global__ void k_norm(const float* __restrict__ sumPart, float* __restrict__ out, int n) {
    __shared__ float sm[256];
    sm[threadIdx.x] = sumPart[threadIdx.x];
    __syncthreads();
    for (int off = 128; off > 0; off >>= 1) {
        if (threadIdx.x < off) sm[threadIdx.x] += sm[threadIdx.x + off];
        __syncthreads();
    }
    float inv = 1.0f / sm[0];
    for (int i = blockIdx.x * 256 + threadIdx.x; i < n; i += 256 * RED_BLOCKS) out[i] *= inv;
}

extern "C" void kernel_launch(void* const* d_in, const int* in_sizes, int n_in,
                              void* d_out, int out_size, void* d_ws, size_t ws_size,
                              hipStream_t stream) {
    const float* loss = (const float*)d_in[0];   // [N, 200]
    const float* Ws   = (const float*)d_in[1];   // [1, 200]
    const float* Wg   = (const float*)d_in[2];   // [1, 2]
    const int* esrc   = (const int*)d_in[3];     // [E]
    const int* edst   = (const int*)d_in[4];     // [E]
    float* out = (float*)d_out;                  // [N]

    const int n  = in_sizes[0] / 200;
    const int ne = in_sizes[3];
    const int Gh = (n + (NT / 16) - 1) / (NT / 16);

    const int nch = (n + CCH - 1) >> CSH2;              // node chunks
    int split = 256 / nch; if (split < 1) split = 1;    // one full CU round
    const int epb = (((ne + split - 1) / split) + 3) & ~3;

    // ws layout (32-bit words):
    // h[n] | logit[n] | ordArr[n] | maxPart | sumPart | partials[2*nch*split*CCH]
    float*    h        = (float*)d_ws;
    float*    logit    = h + n;
    unsigned* ordArr   = (unsigned*)(logit + n);
    float*    maxPart  = (float*)(ordArr + n);
    float*    sumPart  = maxPart + RED_BLOCKS;
    unsigned* partials = (unsigned*)(sumPart + RED_BLOCKS);
    size_t part_w = (size_t)2 * nch * split * CCH;
    size_t need = ((size_t)3 * n + 2 * RED_BLOCKS + part_w) * 4;

    k_h<<<Gh, NT, 0, stream>>>(loss, Ws, h, ordArr, n);

    if (need <= ws_size) {
        k_accum<<<nch * split, AT, 0, stream>>>(esrc, edst, ordArr, partials, ne, nch, split, epb);
        k_logit_max<<<RED_BLOCKS, 256, 0, stream>>>(h, partials, Wg, logit, maxPart, n, nch, split);
    } else {
        hipMemsetAsync(partials, 0, (size_t)2 * (1 << 17) * 4, stream);
        k_edges_dev<<<(ne + 255) / 256, 256, 0, stream>>>(esrc, edst, h, partials, ne);
        k_logit_max_dev<<<RED_BLOCKS, 256, 0, stream>>>(h, partials, Wg, logit, maxPart, n);
    }

    k_exp_sum<<<RED_BLOCKS, 256, 0, stream>>>(logit, maxPart, out, sumPart, n);
    k_norm<<<RED_BLOCKS, 256, 0, stream>>>(sumPart, out, n);
}